// Round 9
// baseline (263.683 us; speedup 1.0000x reference)
//
#include <hip/hip_runtime.h>

#define NBATCH 16
#define NPTS   2048
#define MQ     2025
#define CWDIM  512
#define NROWS  32400

typedef __attribute__((ext_vector_type(8))) short bf16x8;
typedef __attribute__((ext_vector_type(4))) float f32x4;

// ---------- helpers ----------
__device__ __forceinline__ unsigned fkey(float f) {
  unsigned u = __float_as_uint(f);
  return (u & 0x80000000u) ? ~u : (u | 0x80000000u);
}
__device__ __forceinline__ float funkey(unsigned u) {
  unsigned v = (u & 0x80000000u) ? (u ^ 0x80000000u) : ~u;
  return __uint_as_float(v);
}
__device__ __forceinline__ unsigned short f2bf(float f) {  // RNE f32->bf16
  unsigned u = __float_as_uint(f);
  u = (u + 0x7FFFu + ((u >> 16) & 1u)) >> 16;
  return (unsigned short)u;
}

// =====================================================================
// prep: fused weight-prep + workspace zeroing (1 dispatch)
// blocks: [0,8) ew2 transpose | [8,40) ew3chunk | [40,296) w2chunk |
//         [296,320) zero keys/lacc/h1b
// =====================================================================
__global__ __launch_bounds__(256) void prep_kernel(
    const float* __restrict__ ew2, const float* __restrict__ ew3,
    const float* __restrict__ f1w2, const float* __restrict__ f2w2,
    unsigned short* __restrict__ ew2T, unsigned short* __restrict__ ew3C,
    unsigned short* __restrict__ w2C, unsigned* __restrict__ zws)
{
  __shared__ float tile[32][33];
  const int blk = blockIdx.x;
  const int t = threadIdx.x;

  if (blk < 8) {
    const int kt = blk >> 2, nt = blk & 3;
    const int tx = t & 31, ty = t >> 5;
    #pragma unroll
    for (int j = 0; j < 4; ++j)
      tile[ty + 8 * j][tx] = ew2[(size_t)(kt * 32 + ty + 8 * j) * 128 + nt * 32 + tx];
    __syncthreads();
    #pragma unroll
    for (int j = 0; j < 4; ++j)
      ew2T[(size_t)(nt * 32 + ty + 8 * j) * 64 + kt * 32 + tx] = f2bf(tile[tx][ty + 8 * j]);
  } else if (blk < 40) {
    const int gid = (blk - 8) * 256 + t;
    const int c16 = gid & 15, hi = (gid >> 4) & 3, cblk = (gid >> 6) & 31, kblk = gid >> 11;
    const int col = cblk * 16 + c16;
    unsigned short tmp[8];
    #pragma unroll
    for (int j = 0; j < 8; ++j)
      tmp[j] = f2bf(ew3[(size_t)(kblk * 32 + hi * 8 + j) * 512 + col]);
    int4 pk;
    pk.x = (int)((unsigned)tmp[0] | ((unsigned)tmp[1] << 16));
    pk.y = (int)((unsigned)tmp[2] | ((unsigned)tmp[3] << 16));
    pk.z = (int)((unsigned)tmp[4] | ((unsigned)tmp[5] << 16));
    pk.w = (int)((unsigned)tmp[6] | ((unsigned)tmp[7] << 16));
    *(int4*)&ew3C[(size_t)gid * 8] = pk;
  } else if (blk < 296) {
    const int gid = (blk - 40) * 256 + t;       // 65536
    const int s = gid >> 15;
    const int rem = gid & 32767;
    const int c16 = rem & 15, hi = (rem >> 4) & 3, cblk = (rem >> 6) & 31, kt = rem >> 11;
    const int col = cblk * 16 + c16;
    const float* src = s ? f2w2 : f1w2;
    unsigned short tmp[8];
    #pragma unroll
    for (int j = 0; j < 8; ++j)
      tmp[j] = f2bf(src[(size_t)(kt * 32 + hi * 8 + j) * 512 + col]);
    int4 pk;
    pk.x = (int)((unsigned)tmp[0] | ((unsigned)tmp[1] << 16));
    pk.y = (int)((unsigned)tmp[2] | ((unsigned)tmp[3] << 16));
    pk.z = (int)((unsigned)tmp[4] | ((unsigned)tmp[5] << 16));
    pk.w = (int)((unsigned)tmp[6] | ((unsigned)tmp[7] << 16));
    *(int4*)&w2C[(size_t)s * 262144 + (size_t)rem * 8] = pk;
  } else {
    const int idx = (blk - 296) * 256 + t;      // 6144 threads
    for (int i = idx; i < 24640; i += 6144) zws[i] = 0u;
  }
}

// =====================================================================
// Encoder (MFMA): block = 64 points, 512 thr = 8 waves. (unchanged, passed)
// =====================================================================
__global__ __launch_bounds__(512, 2) void enc2_kernel(
    const float* __restrict__ pts,
    const float* __restrict__ ew1, const float* __restrict__ eb1,
    const unsigned short* __restrict__ ew2T, const float* __restrict__ eb2,
    const unsigned short* __restrict__ ew3C, const float* __restrict__ eb3,
    unsigned* __restrict__ keys)
{
  __shared__ unsigned short h1s[64 * 64];
  __shared__ unsigned short h2s[64 * 128];
  __shared__ float s_pts[64][4];
  const int t = threadIdx.x;
  const int b = blockIdx.x >> 5, p0 = (blockIdx.x & 31) << 6;
  if (t < 64)
    *(float4*)&s_pts[t][0] = *(const float4*)(pts + ((size_t)b * NPTS + p0 + t) * 4);
  __syncthreads();

  {
    const int c = t & 63;
    const float w0 = ew1[c], w1 = ew1[64 + c], w2 = ew1[128 + c], w3 = ew1[192 + c];
    const float bb = eb1[c];
    #pragma unroll
    for (int i = 0; i < 8; ++i) {
      const int p = i * 8 + (t >> 6);
      float acc = bb + s_pts[p][0] * w0 + s_pts[p][1] * w1 + s_pts[p][2] * w2 + s_pts[p][3] * w3;
      unsigned byte = ((unsigned)p << 7) + ((unsigned)c << 1);
      byte ^= ((unsigned)(p & 7)) << 4;
      h1s[byte >> 1] = f2bf(fmaxf(acc, 0.f));
    }
  }
  __syncthreads();

  const int wv = t >> 6, lane = t & 63, l15 = lane & 15, hi = lane >> 4;

  {
    f32x4 acc[4];
    #pragma unroll
    for (int m = 0; m < 4; ++m) acc[m] = (f32x4){0.f, 0.f, 0.f, 0.f};
    const int col = 16 * wv + l15;
    #pragma unroll
    for (int kk = 0; kk < 64; kk += 32) {
      bf16x8 bv = *(const bf16x8*)(ew2T + (size_t)col * 64 + kk + hi * 8);
      #pragma unroll
      for (int m = 0; m < 4; ++m) {
        const int row = 16 * m + l15;
        unsigned byte = ((unsigned)row << 7) + ((unsigned)((kk + hi * 8)) << 1);
        byte ^= ((unsigned)(row & 7)) << 4;
        bf16x8 av = *(const bf16x8*)&h1s[byte >> 1];
        acc[m] = __builtin_amdgcn_mfma_f32_16x16x32_bf16(av, bv, acc[m], 0, 0, 0);
      }
    }
    const float b2c = eb2[col];
    #pragma unroll
    for (int m = 0; m < 4; ++m)
      #pragma unroll
      for (int r = 0; r < 4; ++r) {
        const int row = 16 * m + hi * 4 + r;
        unsigned byte = ((unsigned)row << 8) + ((unsigned)col << 1);
        byte ^= ((unsigned)(row & 7)) << 4;
        h2s[byte >> 1] = f2bf(fmaxf(acc[m][r] + b2c, 0.f));
      }
  }
  __syncthreads();

  {
    f32x4 acc[4][4];
    #pragma unroll
    for (int m = 0; m < 4; ++m)
      #pragma unroll
      for (int n = 0; n < 4; ++n) acc[m][n] = (f32x4){0.f, 0.f, 0.f, 0.f};
    #pragma unroll
    for (int kk = 0; kk < 128; kk += 32) {
      bf16x8 av[4];
      #pragma unroll
      for (int m = 0; m < 4; ++m) {
        const int row = 16 * m + l15;
        unsigned byte = ((unsigned)row << 8) + ((unsigned)(kk + hi * 8) << 1);
        byte ^= ((unsigned)(row & 7)) << 4;
        av[m] = *(const bf16x8*)&h2s[byte >> 1];
      }
      #pragma unroll
      for (int n = 0; n < 4; ++n) {
        bf16x8 bv = *(const bf16x8*)(ew3C +
            (size_t)(((kk >> 5) * 32 + 4 * wv + n) * 512) + lane * 8);
        #pragma unroll
        for (int m = 0; m < 4; ++m)
          acc[m][n] = __builtin_amdgcn_mfma_f32_16x16x32_bf16(av[m], bv, acc[m][n], 0, 0, 0);
      }
    }
    #pragma unroll
    for (int n = 0; n < 4; ++n) {
      const int col = 64 * wv + 16 * n + l15;
      float mx = -1e30f;
      #pragma unroll
      for (int m = 0; m < 4; ++m)
        #pragma unroll
        for (int r = 0; r < 4; ++r) mx = fmaxf(mx, acc[m][n][r]);
      mx = fmaxf(mx, __shfl_xor(mx, 16));
      mx = fmaxf(mx, __shfl_xor(mx, 32));
      if (hi == 0) atomicMax(&keys[b * CWDIM + col], fkey(mx + eb3[col]));
    }
  }
}

// =====================================================================
// h1base (+ fused theta decode): split-K x2, atomicAdd partials.
// =====================================================================
__global__ __launch_bounds__(256) void h1base_kernel(
    const unsigned* __restrict__ keys, float* __restrict__ theta_out,
    const float* __restrict__ f1w1, const float* __restrict__ f1b1,
    const float* __restrict__ f2w1, const float* __restrict__ f2b1,
    float* __restrict__ h1b)
{
  __shared__ float thl[256];
  const int t = threadIdx.x;
  const int gid = blockIdx.x * 256 + t;   // 32768
  const int half = gid >> 14;
  const int rem = gid & 16383;
  const int stage = rem >> 13, bb = (rem >> 9) & 15, c = rem & 511;
  thl[t] = funkey(keys[bb * 512 + half * 256 + t]);
  if (gid < 8192) theta_out[gid] = funkey(keys[gid]);
  __syncthreads();
  const float* w = stage ? f2w1 : f1w1;
  float acc = (half == 0) ? (stage ? f2b1[c] : f1b1[c]) : 0.f;
  const float* wp = w + (size_t)(half * 256) * 512 + c;
  #pragma unroll 8
  for (int k = 0; k < 256; ++k) acc += thl[k] * wp[(size_t)k * 512];
  atomicAdd(&h1b[rem], acc);
}

// =====================================================================
// fold6: BM=64 (507 blocks), 8 waves = 1M x 8N (wave = 64 rows x 64 cols,
// single pass over N=512). B streamed per-wave to registers from chunked
// w2C (1KB contiguous loads, no duplication) -> zero K-loop barriers.
// =====================================================================
struct Fold6Smem {
  unsigned short sA[64 * 512];   // 64 KB
  float red[8][64][3];           // 6 KB
  float ext[64][4];              // 1 KB
  int   rowbb[64];               // 256 B
};

template <int ST>
__device__ __forceinline__ void fold6_stage(Fold6Smem& S, int t, int r0,
    const float* __restrict__ h1bg,
    const float* __restrict__ w1,
    const unsigned short* __restrict__ wst,
    const float* __restrict__ b2, const float* __restrict__ w3,
    const float* __restrict__ b3, float* __restrict__ out_pc)
{
  constexpr int NE = ST ? 3 : 2;
  const int wv = t >> 6, lane = t & 63, l15 = lane & 15, hi = lane >> 4;

  __syncthreads();   // ext (grid init or prev-stage epilogue) ready

  // ---- A-build: 64x512 tile -> sA (fragment-contiguous), once per stage
  {
    const int row = t & 63;
    const int bb = S.rowbb[row];
    const float e0 = S.ext[row][0], e1 = S.ext[row][1];
    float e2 = 0.f;
    if (NE == 3) e2 = S.ext[row][2];
    const float* hb  = h1bg + ST * 8192 + bb * 512;
    const float* wr0 = w1 + (size_t)512 * 512;
    const float* wr1 = wr0 + 512;
    const float* wr2 = wr1 + 512;
    #pragma unroll
    for (int i = 0; i < 8; ++i) {
      const int ko = (t >> 6) * 8 + i;
      const int c0 = ko * 8;
      float v[8];
      #pragma unroll
      for (int hf = 0; hf < 2; ++hf) {
        float4 h = *(const float4*)(hb + c0 + hf * 4);
        float4 a = *(const float4*)(wr0 + c0 + hf * 4);
        float4 bq = *(const float4*)(wr1 + c0 + hf * 4);
        v[hf * 4 + 0] = h.x + e0 * a.x + e1 * bq.x;
        v[hf * 4 + 1] = h.y + e0 * a.y + e1 * bq.y;
        v[hf * 4 + 2] = h.z + e0 * a.z + e1 * bq.z;
        v[hf * 4 + 3] = h.w + e0 * a.w + e1 * bq.w;
        if (NE == 3) {
          float4 cq = *(const float4*)(wr2 + c0 + hf * 4);
          v[hf * 4 + 0] += e2 * cq.x; v[hf * 4 + 1] += e2 * cq.y;
          v[hf * 4 + 2] += e2 * cq.z; v[hf * 4 + 3] += e2 * cq.w;
        }
      }
      int4 pk;
      pk.x = (int)((unsigned)f2bf(fmaxf(v[0], 0.f)) | ((unsigned)f2bf(fmaxf(v[1], 0.f)) << 16));
      pk.y = (int)((unsigned)f2bf(fmaxf(v[2], 0.f)) | ((unsigned)f2bf(fmaxf(v[3], 0.f)) << 16));
      pk.z = (int)((unsigned)f2bf(fmaxf(v[4], 0.f)) | ((unsigned)f2bf(fmaxf(v[5], 0.f)) << 16));
      pk.w = (int)((unsigned)f2bf(fmaxf(v[6], 0.f)) | ((unsigned)f2bf(fmaxf(v[7], 0.f)) << 16));
      *(int4*)&S.sA[(unsigned)(((ko >> 2) * 4 + (row >> 4)) * 512 + (ko & 3) * 128 + (row & 15) * 8)] = pk;
    }
  }
  __syncthreads();

  // ---- K-loop: wave owns cols [64*wv, 64*wv+64), all 64 rows, K=512
  f32x4 acc[4][4];
  #pragma unroll
  for (int m = 0; m < 4; ++m)
    #pragma unroll
    for (int n = 0; n < 4; ++n) acc[m][n] = (f32x4){0.f, 0.f, 0.f, 0.f};

  const unsigned short* wb = wst + (size_t)(4 * wv) * 512 + lane * 8;

  #pragma unroll 2
  for (int kt = 0; kt < 16; ++kt) {
    bf16x8 bv[4];
    #pragma unroll
    for (int n = 0; n < 4; ++n)
      bv[n] = *(const bf16x8*)(wb + (size_t)(kt * 32 + n) * 512);
    bf16x8 a[4];
    #pragma unroll
    for (int m = 0; m < 4; ++m)
      a[m] = *(const bf16x8*)&S.sA[(unsigned)(kt * 4 + m) * 512 + (unsigned)lane * 8];
    __builtin_amdgcn_s_setprio(1);
    #pragma unroll
    for (int n = 0; n < 4; ++n)
      #pragma unroll
      for (int m = 0; m < 4; ++m)
        acc[m][n] = __builtin_amdgcn_mfma_f32_16x16x32_bf16(a[m], bv[n], acc[m][n], 0, 0, 0);
    __builtin_amdgcn_s_setprio(0);
  }

  // ---- layer-3 partials
  float p[4][4][3];
  #pragma unroll
  for (int m = 0; m < 4; ++m)
    #pragma unroll
    for (int r = 0; r < 4; ++r)
      #pragma unroll
      for (int jj = 0; jj < 3; ++jj) p[m][r][jj] = 0.f;

  #pragma unroll
  for (int n = 0; n < 4; ++n) {
    const int colG = 64 * wv + 16 * n + l15;
    const float b2c = b2[colG];
    const float w30 = w3[colG * 3 + 0], w31 = w3[colG * 3 + 1], w32 = w3[colG * 3 + 2];
    #pragma unroll
    for (int m = 0; m < 4; ++m)
      #pragma unroll
      for (int r = 0; r < 4; ++r) {
        const float h = fmaxf(acc[m][n][r] + b2c, 0.f);
        p[m][r][0] += h * w30; p[m][r][1] += h * w31; p[m][r][2] += h * w32;
      }
  }

  #pragma unroll
  for (int m = 0; m < 4; ++m)
    #pragma unroll
    for (int r = 0; r < 4; ++r)
      #pragma unroll
      for (int jj = 0; jj < 3; ++jj) {
        float v = p[m][r][jj];
        v += __shfl_xor(v, 1); v += __shfl_xor(v, 2);
        v += __shfl_xor(v, 4); v += __shfl_xor(v, 8);
        p[m][r][jj] = v;
      }
  if (l15 == 0) {
    #pragma unroll
    for (int m = 0; m < 4; ++m)
      #pragma unroll
      for (int r = 0; r < 4; ++r) {
        const int row = 16 * m + hi * 4 + r;
        S.red[wv][row][0] = p[m][r][0];
        S.red[wv][row][1] = p[m][r][1];
        S.red[wv][row][2] = p[m][r][2];
      }
  }
  __syncthreads();

  if (t < 192) {
    const int row = t / 3, jj = t - (t / 3) * 3;
    float v = b3[jj];
    #pragma unroll
    for (int w = 0; w < 8; ++w) v += S.red[w][row][jj];
    if (ST == 0) S.ext[row][jj] = v;
    else if (r0 + row < NROWS) out_pc[(size_t)(r0 + row) * 3 + jj] = v;
  }
  __syncthreads();
}

__global__ __launch_bounds__(512, 1) void fold6_kernel(
    const float* __restrict__ grid2, const float* __restrict__ h1b,
    const unsigned short* __restrict__ w2C,
    const float* __restrict__ f1w1, const float* __restrict__ f1b2,
    const float* __restrict__ f1w3, const float* __restrict__ f1b3,
    const float* __restrict__ f2w1, const float* __restrict__ f2b2,
    const float* __restrict__ f2w3, const float* __restrict__ f2b3,
    float* __restrict__ out_pc)
{
  __shared__ Fold6Smem S;
  const int t = threadIdx.x;
  const int r0 = blockIdx.x * 64;

  if (t < 64) {
    const int r = r0 + t;
    const int bb = min(r / MQ, NBATCH - 1);
    S.rowbb[t] = bb;
    const int m = min(r - bb * MQ, MQ - 1);
    S.ext[t][0] = grid2[m * 2 + 0];
    S.ext[t][1] = grid2[m * 2 + 1];
    S.ext[t][2] = 0.f;
    S.ext[t][3] = 0.f;
  }

  fold6_stage<0>(S, t, r0, h1b, f1w1, w2C,          f1b2, f1w3, f1b3, nullptr);
  fold6_stage<1>(S, t, r0, h1b, f2w1, w2C + 262144, f2b2, f2w3, f2b3, out_pc);
}

// =====================================================================
// cham: fused chamfer A + B + finalize; expanded form d2 = |b|^2-2ab+|a|^2
// (matches reference's einsum expansion). 3 FMA + min per pair.
// blocks [0,512): A-side | [512,1024): B-side; completion counter -> loss.
// =====================================================================
__global__ __launch_bounds__(256) void cham_kernel(
    const float* __restrict__ pts, const float* __restrict__ pc,
    float* __restrict__ lacc, float* __restrict__ loss)
{
  __shared__ float s0[2048], s1[2048], s2[2048], s3[2048];
  const int t = threadIdx.x;
  const int side = blockIdx.x >> 9;
  const int ib = blockIdx.x & 511;
  const int b = ib >> 5;

  if (side == 0) {
    // ---- stage pc (targets) + |b|^2; pad with large-finite (NaN-safe)
    const int n0 = (ib & 31) << 6;
    const float* pcb = pc + (size_t)b * (MQ * 3);
    for (int i = t; i < MQ * 3; i += 256) {
      float v = pcb[i];
      int m = i / 3, j = i - m * 3;
      if (j == 0) s0[m] = v; else if (j == 1) s1[m] = v; else s2[m] = v;
    }
    for (int i = MQ + t; i < 2048; i += 256) { s0[i] = 100.f; s1[i] = 100.f; s2[i] = 100.f; }
    __syncthreads();
    for (int i = t; i < 2048; i += 256)
      s3[i] = s0[i] * s0[i] + s1[i] * s1[i] + s2[i] * s2[i];
    __syncthreads();

    const int pid = t >> 4, q = t & 15;
    float nx[4], ny[4], nz[4], a2[4], mn[4];
    #pragma unroll
    for (int j = 0; j < 4; ++j) {
      const int n = n0 + pid * 4 + j;
      float4 P = *(const float4*)(pts + ((size_t)b * NPTS + n) * 4);
      const float az = P.z + P.w;
      nx[j] = -2.f * P.x; ny[j] = -2.f * P.y; nz[j] = -2.f * az;
      a2[j] = P.x * P.x + P.y * P.y + az * az;
      mn[j] = 1e30f;
    }
    #pragma unroll 4
    for (int i = 0; i < 32; ++i) {
      const int m4 = q * 4 + i * 64;
      float4 bx = *(const float4*)&s0[m4];
      float4 by = *(const float4*)&s1[m4];
      float4 bz = *(const float4*)&s2[m4];
      float4 bq = *(const float4*)&s3[m4];
      #pragma unroll
      for (int j = 0; j < 4; ++j) {
        float d0 = fmaf(nx[j], bx.x, fmaf(ny[j], by.x, fmaf(nz[j], bz.x, bq.x)));
        float d1 = fmaf(nx[j], bx.y, fmaf(ny[j], by.y, fmaf(nz[j], bz.y, bq.y)));
        float d2 = fmaf(nx[j], bx.z, fmaf(ny[j], by.z, fmaf(nz[j], bz.z, bq.z)));
        float d3 = fmaf(nx[j], bx.w, fmaf(ny[j], by.w, fmaf(nz[j], bz.w, bq.w)));
        mn[j] = fminf(mn[j], fminf(fminf(d0, d1), fminf(d2, d3)));
      }
    }
    #pragma unroll
    for (int j = 0; j < 4; ++j) {
      mn[j] = fminf(mn[j], __shfl_xor(mn[j], 1));
      mn[j] = fminf(mn[j], __shfl_xor(mn[j], 2));
      mn[j] = fminf(mn[j], __shfl_xor(mn[j], 4));
      mn[j] = fminf(mn[j], __shfl_xor(mn[j], 8));
    }
    float v = 0.f;
    if (q == 0) {
      #pragma unroll
      for (int j = 0; j < 4; ++j) v += fmaxf(mn[j] + a2[j], 0.f);
    }
    v += __shfl_xor(v, 16); v += __shfl_xor(v, 32);
    if ((t & 63) == 0) atomicAdd(lacc, v);
  } else {
    // ---- stage pts (targets) + |a|^2 (all 2048 valid)
    const int m0 = (ib & 31) << 6;
    for (int i = t; i < NPTS; i += 256) {
      float4 pp = *(const float4*)(pts + ((size_t)b * NPTS + i) * 4);
      const float az = pp.z + pp.w;
      s0[i] = pp.x; s1[i] = pp.y; s2[i] = az;
      s3[i] = pp.x * pp.x + pp.y * pp.y + az * az;
    }
    __syncthreads();

    const int pid = t >> 4, q = t & 15;
    float nx[4], ny[4], nz[4], b2r[4], mn[4];
    bool vld[4];
    #pragma unroll
    for (int j = 0; j < 4; ++j) {
      const int m = m0 + pid * 4 + j;
      vld[j] = (m < MQ);
      const int mc = vld[j] ? m : (MQ - 1);
      const float bx = pc[(size_t)b * (MQ * 3) + mc * 3 + 0];
      const float by = pc[(size_t)b * (MQ * 3) + mc * 3 + 1];
      const float bz = pc[(size_t)b * (MQ * 3) + mc * 3 + 2];
      nx[j] = -2.f * bx; ny[j] = -2.f * by; nz[j] = -2.f * bz;
      b2r[j] = bx * bx + by * by + bz * bz;
      mn[j] = 1e30f;
    }
    #pragma unroll 4
    for (int i = 0; i < 32; ++i) {
      const int n4 = q * 4 + i * 64;
      float4 ax = *(const float4*)&s0[n4];
      float4 ay = *(const float4*)&s1[n4];
      float4 az = *(const float4*)&s2[n4];
      float4 aq = *(const float4*)&s3[n4];
      #pragma unroll
      for (int j = 0; j < 4; ++j) {
        float d0 = fmaf(nx[j], ax.x, fmaf(ny[j], ay.x, fmaf(nz[j], az.x, aq.x)));
        float d1 = fmaf(nx[j], ax.y, fmaf(ny[j], ay.y, fmaf(nz[j], az.y, aq.y)));
        float d2 = fmaf(nx[j], ax.z, fmaf(ny[j], ay.z, fmaf(nz[j], az.z, aq.z)));
        float d3 = fmaf(nx[j], ax.w, fmaf(ny[j], ay.w, fmaf(nz[j], az.w, aq.w)));
        mn[j] = fminf(mn[j], fminf(fminf(d0, d1), fminf(d2, d3)));
      }
    }
    #pragma unroll
    for (int j = 0; j < 4; ++j) {
      mn[j] = fminf(mn[j], __shfl_xor(mn[j], 1));
      mn[j] = fminf(mn[j], __shfl_xor(mn[j], 2));
      mn[j] = fminf(mn[j], __shfl_xor(mn[j], 4));
      mn[j] = fminf(mn[j], __shfl_xor(mn[j], 8));
    }
    float v = 0.f;
    if (q == 0) {
      #pragma unroll
      for (int j = 0; j < 4; ++j) if (vld[j]) v += fmaxf(mn[j] + b2r[j], 0.f);
    }
    v += __shfl_xor(v, 16); v += __shfl_xor(v, 32);
    if ((t & 63) == 0) atomicAdd(lacc + 1, v);
  }

  // ---- completion counter -> last block finalizes loss
  __syncthreads();
  if (t == 0) {
    __threadfence();
    unsigned old = atomicAdd((unsigned*)(lacc + 2), 1u);
    if (old == 1023u) {
      float l0 = atomicAdd(lacc, 0.f);
      float l1 = atomicAdd(lacc + 1, 0.f);
      loss[0] = l0 * (1.0f / (NBATCH * NPTS)) + l1 * (1.0f / (NBATCH * MQ));
    }
  }
}

// =====================================================================
extern "C" void kernel_launch(void* const* d_in, const int* in_sizes, int n_in,
                              void* d_out, int out_size, void* d_ws, size_t ws_size,
                              hipStream_t stream) {
  const float* pts  = (const float*)d_in[0];
  const float* ew1  = (const float*)d_in[1];
  const float* eb1  = (const float*)d_in[2];
  const float* ew2  = (const float*)d_in[3];
  const float* eb2  = (const float*)d_in[4];
  const float* ew3  = (const float*)d_in[5];
  const float* eb3  = (const float*)d_in[6];
  const float* f1w1 = (const float*)d_in[7];
  const float* f1b1 = (const float*)d_in[8];
  const float* f1w2 = (const float*)d_in[9];
  const float* f1b2 = (const float*)d_in[10];
  const float* f1w3 = (const float*)d_in[11];
  const float* f1b3 = (const float*)d_in[12];
  const float* f2w1 = (const float*)d_in[13];
  const float* f2b1 = (const float*)d_in[14];
  const float* f2w2 = (const float*)d_in[15];
  const float* f2b2 = (const float*)d_in[16];
  const float* f2w3 = (const float*)d_in[17];
  const float* f2b3 = (const float*)d_in[18];
  const float* grid2= (const float*)d_in[19];

  float* out = (float*)d_out;
  unsigned* keys       = (unsigned*)d_ws;                              // 32768 B
  float* lacc          = (float*)((char*)d_ws + 32768);                // 256 B
  float* h1b           = (float*)((char*)d_ws + 33024);                // 65536 B
  unsigned short* w2C  = (unsigned short*)((char*)d_ws + 98560);       // 1 MB
  unsigned short* ew2T = (unsigned short*)((char*)d_ws + 1147136);     // 16 KB
  unsigned short* ew3C = (unsigned short*)((char*)d_ws + 1163520);     // 128 KB

  prep_kernel<<<320, 256, 0, stream>>>(ew2, ew3, f1w2, f2w2,
                                       ew2T, ew3C, w2C, (unsigned*)d_ws);
  enc2_kernel<<<512, 512, 0, stream>>>(pts, ew1, eb1, ew2T, eb2, ew3C, eb3, keys);
  h1base_kernel<<<128, 256, 0, stream>>>(keys, out, f1w1, f1b1, f2w1, f2b1, h1b);
  fold6_kernel<<<507, 512, 0, stream>>>(grid2, h1b, w2C,
                                        f1w1, f1b2, f1w3, f1b3,
                                        f2w1, f2b2, f2w3, f2b3,
                                        out + 8192);                   // pc_out
  cham_kernel<<<1024, 256, 0, stream>>>(pts, out + 8192, lacc,
                                        out + 8192 + 97200);           // loss
}